// Round 1
// 244.485 us; speedup vs baseline: 1.0886x; 1.0886x over previous
//
#include <hip/hip_runtime.h>
#include <hip/hip_bf16.h>
#include <math.h>

#define N_TOK 8192
#define DIM   1024
#define NEXP  16
#define TOPK  2
#define CAPE  1024
#define NSLOT (N_TOK*TOPK)

typedef __attribute__((ext_vector_type(8))) short     short8;
typedef __attribute__((ext_vector_type(4))) float     floatx4;
typedef __attribute__((ext_vector_type(4))) unsigned short ushort4v;

__device__ __forceinline__ unsigned short f2bf(float f) {
    unsigned u = __float_as_uint(f);
    u += 0x7FFFu + ((u >> 16) & 1u);   // round-to-nearest-even
    return (unsigned short)(u >> 16);
}

// async global->LDS, 16B per lane; LDS dest = wave-uniform base + lane*16
#define GLOAD_LDS16(g, l) __builtin_amdgcn_global_load_lds( \
    (const __attribute__((address_space(1))) unsigned int*)(g), \
    (__attribute__((address_space(3))) unsigned int*)(l), 16, 0, 0)

#define RAW_BARRIER() asm volatile("s_barrier" ::: "memory")

// ---------------- gw transpose: [D,E] -> [E,D] (64 KB, one-shot) -----------
__global__ void gwt_kernel(const float* __restrict__ gw, float* __restrict__ gwT) {
    int i = blockIdx.x * 256 + threadIdx.x;
    if (i >= DIM * NEXP) return;
    int d = i >> 4, e = i & 15;
    gwT[e * DIM + d] = gw[i];
}

// ------- gate: logits -> top2 -> softmax -> slot records; fused x->bf16 ----
__global__ __launch_bounds__(256) void gate_kernel(
        const float* __restrict__ x,
        const float* __restrict__ gwT,
        const float* __restrict__ gb,
        int* __restrict__ slot_expert,
        unsigned long long* __restrict__ slot_key,
        float* __restrict__ slot_gate,
        unsigned short* __restrict__ Xb) {
    const int t    = blockIdx.x * 4 + (threadIdx.x >> 6);
    const int lane = threadIdx.x & 63;

    const floatx4* xr = (const floatx4*)(x + (size_t)t * DIM);
    ushort4v* Xb4 = (ushort4v*)Xb + (size_t)t * 256;
    floatx4 xv[4];
#pragma unroll
    for (int i = 0; i < 4; i++) {
        xv[i] = xr[lane + i * 64];
        ushort4v o;
        o[0] = f2bf(xv[i][0]); o[1] = f2bf(xv[i][1]);
        o[2] = f2bf(xv[i][2]); o[3] = f2bf(xv[i][3]);
        Xb4[lane + i * 64] = o;
    }

    float acc[NEXP];
#pragma unroll
    for (int e = 0; e < NEXP; e++) {
        const floatx4* wr = (const floatx4*)(gwT + (size_t)e * DIM);
        float a = 0.f;
#pragma unroll
        for (int i = 0; i < 4; i++) {
            floatx4 w = wr[lane + i * 64];
            a += xv[i][0]*w[0] + xv[i][1]*w[1] + xv[i][2]*w[2] + xv[i][3]*w[3];
        }
        acc[e] = a;
    }
#pragma unroll
    for (int off = 32; off > 0; off >>= 1) {
#pragma unroll
        for (int e = 0; e < NEXP; e++) acc[e] += __shfl_down(acc[e], off, 64);
    }
    if (lane == 0) {
        float v0 = -1e30f; int i0 = 0;
#pragma unroll
        for (int e = 0; e < NEXP; e++) {
            float v = acc[e] + gb[e];
            acc[e] = v;
            if (v > v0) { v0 = v; i0 = e; }   // strict > : lowest index on tie
        }
        float v1 = -1e30f; int i1 = 0;
#pragma unroll
        for (int e = 0; e < NEXP; e++) {
            if (e != i0 && acc[e] > v1) { v1 = acc[e]; i1 = e; }
        }
        float e1 = expf(v1 - v0);
        float den = 1.f + e1;
        float g0 = 1.f / den;       // max gate score (>= 0.5)
        float g1 = e1 / den;
        unsigned sb = __float_as_uint(g0);  // g0 > 0 -> bit order == float order
        int s0 = 2 * t, s1 = 2 * t + 1;
        slot_expert[s0] = i0; slot_expert[s1] = i1;
        slot_gate[s0]   = g0; slot_gate[s1]   = g1;
        unsigned long long hi = ((unsigned long long)sb) << 32;
        slot_key[s0] = hi | (unsigned)(0xFFFFFFFFu - (unsigned)s0);
        slot_key[s1] = hi | (unsigned)(0xFFFFFFFFu - (unsigned)s1);
    }
}

// ------- bucket fill: LDS-aggregated histogram (64 blocks x 256 thr) -------
__global__ __launch_bounds__(256) void bucket_kernel(
        const int* __restrict__ slot_expert,
        const unsigned long long* __restrict__ slot_key,
        int* __restrict__ counts,
        unsigned long long* __restrict__ buckets) {
    __shared__ int lcnt[NEXP];
    __shared__ int lbase[NEXP];
    const int tid = threadIdx.x;
    const int s = blockIdx.x * 256 + tid;
    if (tid < NEXP) lcnt[tid] = 0;
    __syncthreads();
    const int e = slot_expert[s];
    const unsigned long long key = slot_key[s];
    const int lpos = atomicAdd(&lcnt[e], 1);        // LDS atomic: cheap
    __syncthreads();
    if (tid < NEXP) lbase[tid] = lcnt[tid] ? atomicAdd(&counts[tid], lcnt[tid]) : 0;
    __syncthreads();
    buckets[(size_t)e * NSLOT + lbase[e] + lpos] = key;
}

// ---------------- keep mask: one WAVE per slot, lane-parallel rank scan ----
__global__ __launch_bounds__(256) void keep_wave_kernel(
        const int* __restrict__ slot_expert,
        const unsigned long long* __restrict__ slot_key,
        const int* __restrict__ counts,
        const unsigned long long* __restrict__ buckets,
        int* __restrict__ slot_keep) {
    const int wv   = threadIdx.x >> 6;
    const int lane = threadIdx.x & 63;
    const int s    = blockIdx.x * 4 + wv;
    const int e    = slot_expert[s];
    const int c    = counts[e];
    int kp = 1;
    if (c > CAPE) {
        const unsigned long long k = slot_key[s];
        const unsigned long long* bk = buckets + (size_t)e * NSLOT;
        int rank = 0;
        for (int i = lane; i < c; i += 64) rank += (bk[i] > k) ? 1 : 0;
#pragma unroll
        for (int off = 32; off > 0; off >>= 1) rank += __shfl_down(rank, off, 64);
        kp = (__shfl(rank, 0, 64) < CAPE) ? 1 : 0;
    }
    if (lane == 0) slot_keep[s] = kp;
}

// ---- compact: elist (+slot_pos), LDS-aggregated (64 blocks x 256 thr) -----
__global__ __launch_bounds__(256) void compact_kernel(
        const int* __restrict__ slot_expert,
        const int* __restrict__ slot_keep,
        int* __restrict__ ecount,
        int* __restrict__ elist,
        int* __restrict__ slot_pos) {
    __shared__ int lcnt[NEXP];
    __shared__ int lbase[NEXP];
    const int tid = threadIdx.x;
    const int s = blockIdx.x * 256 + tid;
    if (tid < NEXP) lcnt[tid] = 0;
    __syncthreads();
    const int e  = slot_expert[s];
    const int kp = slot_keep[s];
    int lpos = 0;
    if (kp) lpos = atomicAdd(&lcnt[e], 1);
    __syncthreads();
    if (tid < NEXP) lbase[tid] = lcnt[tid] ? atomicAdd(&ecount[tid], lcnt[tid]) : 0;
    __syncthreads();
    if (kp) {
        int p = lbase[e] + lpos;
        elist[e * CAPE + p] = s;
        if (slot_pos) slot_pos[s] = e * CAPE + p;
    }
}

// ------- base (atomic-fallback path only): out[t] = (dropped g sum)*x[t] ---
__global__ void base_kernel(const float* __restrict__ x,
                            const int* __restrict__ keep,
                            const float* __restrict__ gate,
                            float* __restrict__ out) {
    int i = blockIdx.x * blockDim.x + threadIdx.x;   // float4 index
    int t = i >> 8;                                  // 256 float4 per row
    float c = 0.f;
    if (!keep[2 * t])     c += gate[2 * t];
    if (!keep[2 * t + 1]) c += gate[2 * t + 1];
    floatx4 v = ((const floatx4*)x)[i];
    ((floatx4*)out)[i] = v * c;
}

// ---------------- fp32 -> bf16 conversion (weights) ------------------------
__global__ void cvt_kernel(const float* __restrict__ src,
                           unsigned short* __restrict__ dst, int n4) {
    int i = blockIdx.x * blockDim.x + threadIdx.x;
    if (i >= n4) return;
    floatx4 v = ((const floatx4*)src)[i];
    ushort4v o;
    o[0] = f2bf(v[0]); o[1] = f2bf(v[1]); o[2] = f2bf(v[2]); o[3] = f2bf(v[3]);
    ((ushort4v*)dst)[i] = o;
}

// ---------------- grouped expert GEMM: 256^2 tile, BK=64, 8 waves ----------
// T2+T3+T4+T5: double-buffered 128KB LDS, counted-vmcnt prefetch (never
// drained to 0 in steady state), XOR bank swizzle, setprio around MFMA.
//
// LDS layout per operand tile: 256 rows x 64 bf16 (128B rows). K-block j
// (16B units, j in [0,8)) of row r sits at position j ^ (r&7)  ->  the
// ds_read_b128 fragment reads (rows base+l15, col (kk*4+q)*16B) hit 8
// distinct 16B slots per 8-lane group (conflict-free). Achieved with a
// LINEAR global_load_lds destination + inverse-swizzled GLOBAL source
// (rule: swizzle both sides or neither).
//
// Schedule per K-tile t (buffers: tile t uses buf t&1):
//   P0: ds_read A-half(own) + B fj0,1 ; issue B(t+1) g0,g1 ; bar; 16 MFMA; bar
//   P1: ds_read B fj2,3              ; issue B(t+1) g2,g3 ; bar; 16 MFMA; bar
//   P2: ds_read A-half(own, hi 64r)  ;                      bar; 32 MFMA; bar
//   boundary: issue A(t+2) g0..g3 (buf t&1 is read-complete: every wave's
//             lgkmcnt(0) preceded its P2 MFMA, which preceded the P2 end
//             barrier); s_waitcnt vmcnt(4)  -> tile t+1 fully landed, the 4
//             A(t+2) loads stay in flight across the barrier.
template <bool STORE_YS>
__global__ __launch_bounds__(512, 2)
void moe_gemm(const unsigned short* __restrict__ Xb,
              const unsigned short* __restrict__ Wb,
              const float* __restrict__ eb,
              const int* __restrict__ elist,
              const int* __restrict__ ecount,
              const float* __restrict__ slot_gate,
              float* __restrict__ ys,
              float* __restrict__ out) {
    __shared__ unsigned short As[2][256 * 64];   // 64 KB
    __shared__ unsigned short Bs[2][256 * 64];   // 64 KB

    const int e  = blockIdx.z;
    const int ne = ecount[e];
    const int m0 = blockIdx.y * 256;
    if (m0 >= ne) return;
    const int n0   = blockIdx.x * 256;
    const int tid  = threadIdx.x;
    const int wv   = tid >> 6;
    const int lane = tid & 63;
    const int q    = lane >> 4;
    const int l15  = lane & 15;
    const int wr   = wv & 1;    // M half   (rows wr*128 .. +128)
    const int wc   = wv >> 1;   // N quarter (cols wc*64 .. +64)

    // --- staging source pointers (K-invariant). Load g covers rows
    // [g*64, g*64+64); this thread writes 16B at row srow, k-pos (lane&7),
    // so its global source k-block is (lane&7) ^ (row&7).
    const int srow = wv * 8 + (lane >> 3);
    const int jsrc = (lane & 7) ^ (srow & 7);
    const unsigned short* gA[4];
    const unsigned short* gB[4];
#pragma unroll
    for (int g = 0; g < 4; g++) {
        int arow = g * 64 + srow;
        int m    = m0 + arow;
        int slot = elist[e * CAPE + (m < ne ? m : 0)];
        gA[g] = Xb + (size_t)(slot >> 1) * DIM + jsrc * 8;
        gB[g] = Wb + (size_t)e * DIM * DIM + (size_t)(n0 + arow) * DIM + jsrc * 8;
    }

#define STAGE_A4(b, k0) do { \
    GLOAD_LDS16(gA[0] + (k0), &As[b][0 * 4096 + wv * 512]); \
    GLOAD_LDS16(gA[1] + (k0), &As[b][1 * 4096 + wv * 512]); \
    GLOAD_LDS16(gA[2] + (k0), &As[b][2 * 4096 + wv * 512]); \
    GLOAD_LDS16(gA[3] + (k0), &As[b][3 * 4096 + wv * 512]); } while (0)
#define STAGE_B2(b, g0, k0) do { \
    GLOAD_LDS16(gB[g0] + (k0),     &Bs[b][(g0) * 4096 + wv * 512]); \
    GLOAD_LDS16(gB[(g0)+1] + (k0), &Bs[b][((g0)+1) * 4096 + wv * 512]); } while (0)

    // --- prologue: tile0 A+B -> buf0, tile1 A -> buf1; wait tile0 (8 oldest)
    STAGE_A4(0, 0);
    STAGE_B2(0, 0, 0); STAGE_B2(0, 2, 0);
    STAGE_A4(1, 64);
    asm volatile("s_waitcnt vmcnt(4)" ::: "memory");
    __builtin_amdgcn_sched_barrier(0);
    RAW_BARRIER();

    const int swz0 = (q ^ (l15 & 7)) * 8;         // kk=0 read swizzle (shorts)
    const int swz1 = ((4 + q) ^ (l15 & 7)) * 8;   // kk=1
    const int arow_s = (wr * 128 + l15) * 64;     // fi=0 row, short offset
    const int brow_s = (wc * 64 + l15) * 64;      // fj=0 row

    floatx4 acc[8][4] = {};
    short8 a[4][2], b[4][2];

    for (int t = 0; t < 16; t++) {
        const unsigned short* A_ = &As[t & 1][0];
        const unsigned short* B_ = &Bs[t & 1][0];
        const int nb = (t & 1) ^ 1;
        const int k1 = (t + 1) * 64;
        const int k2 = (t + 2) * 64;

        // ---- phase 0: A-half(lo) + B fj0,1 ; stage B(t+1) g0,g1 ----
#pragma unroll
        for (int fi = 0; fi < 4; fi++) {
            a[fi][0] = *(const short8*)(A_ + arow_s + fi * 1024 + swz0);
            a[fi][1] = *(const short8*)(A_ + arow_s + fi * 1024 + swz1);
        }
#pragma unroll
        for (int fj = 0; fj < 2; fj++) {
            b[fj][0] = *(const short8*)(B_ + brow_s + fj * 1024 + swz0);
            b[fj][1] = *(const short8*)(B_ + brow_s + fj * 1024 + swz1);
        }
        if (t + 1 < 16) STAGE_B2(nb, 0, k1);
        RAW_BARRIER();
        __builtin_amdgcn_s_setprio(1);
#pragma unroll
        for (int fi = 0; fi < 4; fi++)
#pragma unroll
            for (int fj = 0; fj < 2; fj++) {
                acc[fi][fj] = __builtin_amdgcn_mfma_f32_16x16x32_bf16(
                    a[fi][0], b[fj][0], acc[fi][fj], 0, 0, 0);
                acc[fi][fj] = __builtin_amdgcn_mfma_f32_16x16x32_bf16(
                    a[fi][1], b[fj][1], acc[fi][fj], 0, 0, 0);
            }
        __builtin_amdgcn_s_setprio(0);
        RAW_BARRIER();

        // ---- phase 1: B fj2,3 ; stage B(t+1) g2,g3 ----
#pragma unroll
        for (int fj = 2; fj < 4; fj++) {
            b[fj][0] = *(const short8*)(B_ + brow_s + fj * 1024 + swz0);
            b[fj][1] = *(const short8*)(B_ + brow_s + fj * 1024 + swz1);
        }
        if (t + 1 < 16) STAGE_B2(nb, 2, k1);
        RAW_BARRIER();
        __builtin_amdgcn_s_setprio(1);
#pragma unroll
        for (int fi = 0; fi < 4; fi++)
#pragma unroll
            for (int fj = 2; fj < 4; fj++) {
                acc[fi][fj] = __builtin_amdgcn_mfma_f32_16x16x32_bf16(
                    a[fi][0], b[fj][0], acc[fi][fj], 0, 0, 0);
                acc[fi][fj] = __builtin_amdgcn_mfma_f32_16x16x32_bf16(
                    a[fi][1], b[fj][1], acc[fi][fj], 0, 0, 0);
            }
        __builtin_amdgcn_s_setprio(0);
        RAW_BARRIER();

        // ---- phase 2: A-half(hi); all fj ----
#pragma unroll
        for (int fi = 0; fi < 4; fi++) {
            a[fi][0] = *(const short8*)(A_ + arow_s + 4096 + fi * 1024 + swz0);
            a[fi][1] = *(const short8*)(A_ + arow_s + 4096 + fi * 1024 + swz1);
        }
        RAW_BARRIER();
        __builtin_amdgcn_s_setprio(1);
#pragma unroll
        for (int fi = 0; fi < 4; fi++)
#pragma unroll
            for (int fj = 0; fj < 4; fj++) {
                acc[fi + 4][fj] = __builtin_amdgcn_mfma_f32_16x16x32_bf16(
                    a[fi][0], b[fj][0], acc[fi + 4][fj], 0, 0, 0);
                acc[fi + 4][fj] = __builtin_amdgcn_mfma_f32_16x16x32_bf16(
                    a[fi][1], b[fj][1], acc[fi + 4][fj], 0, 0, 0);
            }
        __builtin_amdgcn_s_setprio(0);
        RAW_BARRIER();

        // ---- boundary: issue A(t+2) into buf[t&1], counted wait ----
        if (t + 1 < 16) {
            if (t + 2 < 16) {
                STAGE_A4(t & 1, k2);
                asm volatile("s_waitcnt vmcnt(4)" ::: "memory");
            } else {
                asm volatile("s_waitcnt vmcnt(0)" ::: "memory");
            }
            __builtin_amdgcn_sched_barrier(0);
            RAW_BARRIER();
        }
    }
#undef STAGE_A4
#undef STAGE_B2

    // --- epilogue: C/D 16x16 layout col=lane&15, row=q*4+r ---
    float ebv[4];
#pragma unroll
    for (int fj = 0; fj < 4; fj++)
        ebv[fj] = eb[e * DIM + n0 + wc * 64 + fj * 16 + l15];
#pragma unroll
    for (int fi = 0; fi < 8; fi++) {
        const int mrow = m0 + wr * 128 + fi * 16 + q * 4;
#pragma unroll
        for (int r = 0; r < 4; r++) {
            int m = mrow + r;
            if (m >= ne) continue;
            if (STORE_YS) {
                float* yrow = ys + ((size_t)e * CAPE + m) * DIM + n0 + wc * 64;
#pragma unroll
                for (int fj = 0; fj < 4; fj++)
                    yrow[fj * 16 + l15] = acc[fi][fj][r] + ebv[fj];
            } else {
                int slot = elist[e * CAPE + m];
                int tok  = slot >> 1;
                float g  = slot_gate[slot];
                float* orow = out + (size_t)tok * DIM + n0 + wc * 64;
#pragma unroll
                for (int fj = 0; fj < 4; fj++)
                    atomicAdd(orow + fj * 16 + l15, g * (acc[fi][fj][r] + ebv[fj]));
            }
        }
    }
}

// ---------------- combine: out = sum_k g_k * (keep ? ys[pos] : x) ----------
__global__ void combine_kernel(const float* __restrict__ x,
                               const float* __restrict__ ys,
                               const int* __restrict__ keep,
                               const int* __restrict__ pos,
                               const float* __restrict__ gate,
                               float* __restrict__ out) {
    int i = blockIdx.x * 256 + threadIdx.x;   // float4 index
    int t = i >> 8;
    int c = i & 255;
    int s0 = 2 * t, s1 = s0 + 1;
    floatx4 xv = ((const floatx4*)x)[i];
    float g0 = gate[s0], g1 = gate[s1];
    floatx4 r;
    if (keep[s0]) {
        floatx4 y0 = ((const floatx4*)ys)[((size_t)pos[s0] << 8) + c];
        r = y0 * g0;
    } else r = xv * g0;
    if (keep[s1]) {
        floatx4 y1 = ((const floatx4*)ys)[((size_t)pos[s1] << 8) + c];
        r += y1 * g1;
    } else r += xv * g1;
    ((floatx4*)out)[i] = r;
}

extern "C" void kernel_launch(void* const* d_in, const int* in_sizes, int n_in,
                              void* d_out, int out_size, void* d_ws, size_t ws_size,
                              hipStream_t stream) {
    const float* x  = (const float*)d_in[0];   // [N, D]
    const float* gw = (const float*)d_in[1];   // [D, E]
    const float* gb = (const float*)d_in[2];   // [E]
    const float* ew = (const float*)d_in[3];   // [E, D, D]
    const float* eb = (const float*)d_in[4];   // [E, D]
    float* out = (float*)d_out;                // [N, D]

    char* ws = (char*)d_ws;
    // ---- workspace layout (bytes); proven through round 4 ----
    int* counts      = (int*)(ws + 0);                   //    64 B
    int* ecount      = (int*)(ws + 64);                  //    64 B
    int* slot_expert = (int*)(ws + 256);                 //  64 KB
    int* slot_keep   = (int*)(ws + 65792);               //  64 KB
    float* slot_gate = (float*)(ws + 131328);            //  64 KB
    unsigned long long* slot_key = (unsigned long long*)(ws + 196864);  // 128 KB
    unsigned long long* buckets  = (unsigned long long*)(ws + 327936);  //   2 MB
    int* elist       = (int*)(ws + 2425088);             //  64 KB
    float* gwT       = (float*)(ws + 2490624);           //  64 KB
    unsigned short* Xb = (unsigned short*)(ws + 2556160);   // 16 MB
    unsigned short* Wb = (unsigned short*)(ws + 19333376);  // 32 MB -> end 52887808
    int* slot_pos    = (int*)(ws + 52887808);            //  64 KB (ys path only)
    int* ecount2     = (int*)(ws + 52953088);            //  unused pad
    float* ys        = (float*)(ws + 52953344);          //  64 MB (ys path only)
    const size_t WS_NEED_YS = 52953344ull + (size_t)NEXP * CAPE * DIM * 4;  // ~114.5 MB

    const bool ys_path = (ws_size >= WS_NEED_YS);
    (void)ecount2;

    hipMemsetAsync(ws, 0, 256, stream);  // zero counts + ecount

    gwt_kernel <<<64, 256, 0, stream>>>(gw, gwT);
    gate_kernel<<<N_TOK / 4, 256, 0, stream>>>(x, gwT, gb, slot_expert, slot_key,
                                               slot_gate, Xb);
    bucket_kernel<<<NSLOT / 256, 256, 0, stream>>>(slot_expert, slot_key, counts, buckets);
    keep_wave_kernel<<<NSLOT / 4, 256, 0, stream>>>(slot_expert, slot_key, counts,
                                                    buckets, slot_keep);
    compact_kernel<<<NSLOT / 256, 256, 0, stream>>>(slot_expert, slot_keep, ecount, elist,
                                                    ys_path ? slot_pos : nullptr);
    cvt_kernel<<<(NEXP * DIM * DIM / 4) / 256, 256, 0, stream>>>(ew, Wb, NEXP * DIM * DIM / 4);

    if (ys_path) {
        moe_gemm<true><<<dim3(4, 4, 16), 512, 0, stream>>>(Xb, Wb, eb, elist, ecount,
                                                           slot_gate, ys, out);
        combine_kernel<<<N_TOK, 256, 0, stream>>>(x, ys, slot_keep, slot_pos,
                                                  slot_gate, out);
    } else {
        base_kernel<<<(N_TOK * DIM / 4) / 256, 256, 0, stream>>>(x, slot_keep,
                                                                 slot_gate, out);
        moe_gemm<false><<<dim3(4, 4, 16), 512, 0, stream>>>(Xb, Wb, eb, elist, ecount,
                                                            slot_gate, nullptr, out);
    }
}

// Round 2
// 243.750 us; speedup vs baseline: 1.0919x; 1.0030x over previous
//
#include <hip/hip_runtime.h>
#include <hip/hip_bf16.h>
#include <math.h>

#define N_TOK 8192
#define DIM   1024
#define NEXP  16
#define TOPK  2
#define CAPE  1024
#define NSLOT (N_TOK*TOPK)

typedef __attribute__((ext_vector_type(8))) short     short8;
typedef __attribute__((ext_vector_type(4))) float     floatx4;
typedef __attribute__((ext_vector_type(4))) unsigned short ushort4v;

__device__ __forceinline__ unsigned short f2bf(float f) {
    unsigned u = __float_as_uint(f);
    u += 0x7FFFu + ((u >> 16) & 1u);   // round-to-nearest-even
    return (unsigned short)(u >> 16);
}

// async global->LDS, 16B per lane; LDS dest = wave-uniform base + lane*16
#define GLOAD_LDS16(g, l) __builtin_amdgcn_global_load_lds( \
    (const __attribute__((address_space(1))) unsigned int*)(g), \
    (__attribute__((address_space(3))) unsigned int*)(l), 16, 0, 0)

#define RAW_BARRIER() asm volatile("s_barrier" ::: "memory")

// ---------------- gw transpose: [D,E] -> [E,D] (64 KB, one-shot) -----------
__global__ void gwt_kernel(const float* __restrict__ gw, float* __restrict__ gwT) {
    int i = blockIdx.x * 256 + threadIdx.x;
    if (i >= DIM * NEXP) return;
    int d = i >> 4, e = i & 15;
    gwT[e * DIM + d] = gw[i];
}

// ------- gate: logits -> top2 -> softmax -> slot records; fused x->bf16 ----
__global__ __launch_bounds__(256) void gate_kernel(
        const float* __restrict__ x,
        const float* __restrict__ gwT,
        const float* __restrict__ gb,
        int* __restrict__ slot_expert,
        unsigned long long* __restrict__ slot_key,
        float* __restrict__ slot_gate,
        unsigned short* __restrict__ Xb) {
    const int t    = blockIdx.x * 4 + (threadIdx.x >> 6);
    const int lane = threadIdx.x & 63;

    const floatx4* xr = (const floatx4*)(x + (size_t)t * DIM);
    ushort4v* Xb4 = (ushort4v*)Xb + (size_t)t * 256;
    floatx4 xv[4];
#pragma unroll
    for (int i = 0; i < 4; i++) {
        xv[i] = xr[lane + i * 64];
        ushort4v o;
        o[0] = f2bf(xv[i][0]); o[1] = f2bf(xv[i][1]);
        o[2] = f2bf(xv[i][2]); o[3] = f2bf(xv[i][3]);
        Xb4[lane + i * 64] = o;
    }

    float acc[NEXP];
#pragma unroll
    for (int e = 0; e < NEXP; e++) {
        const floatx4* wr = (const floatx4*)(gwT + (size_t)e * DIM);
        float a = 0.f;
#pragma unroll
        for (int i = 0; i < 4; i++) {
            floatx4 w = wr[lane + i * 64];
            a += xv[i][0]*w[0] + xv[i][1]*w[1] + xv[i][2]*w[2] + xv[i][3]*w[3];
        }
        acc[e] = a;
    }
#pragma unroll
    for (int off = 32; off > 0; off >>= 1) {
#pragma unroll
        for (int e = 0; e < NEXP; e++) acc[e] += __shfl_down(acc[e], off, 64);
    }
    if (lane == 0) {
        float v0 = -1e30f; int i0 = 0;
#pragma unroll
        for (int e = 0; e < NEXP; e++) {
            float v = acc[e] + gb[e];
            acc[e] = v;
            if (v > v0) { v0 = v; i0 = e; }   // strict > : lowest index on tie
        }
        float v1 = -1e30f; int i1 = 0;
#pragma unroll
        for (int e = 0; e < NEXP; e++) {
            if (e != i0 && acc[e] > v1) { v1 = acc[e]; i1 = e; }
        }
        float e1 = expf(v1 - v0);
        float den = 1.f + e1;
        float g0 = 1.f / den;       // max gate score (>= 0.5)
        float g1 = e1 / den;
        unsigned sb = __float_as_uint(g0);  // g0 > 0 -> bit order == float order
        int s0 = 2 * t, s1 = 2 * t + 1;
        slot_expert[s0] = i0; slot_expert[s1] = i1;
        slot_gate[s0]   = g0; slot_gate[s1]   = g1;
        unsigned long long hi = ((unsigned long long)sb) << 32;
        slot_key[s0] = hi | (unsigned)(0xFFFFFFFFu - (unsigned)s0);
        slot_key[s1] = hi | (unsigned)(0xFFFFFFFFu - (unsigned)s1);
    }
}

// ------- bucket fill: LDS-aggregated histogram (64 blocks x 256 thr) -------
__global__ __launch_bounds__(256) void bucket_kernel(
        const int* __restrict__ slot_expert,
        const unsigned long long* __restrict__ slot_key,
        int* __restrict__ counts,
        unsigned long long* __restrict__ buckets) {
    __shared__ int lcnt[NEXP];
    __shared__ int lbase[NEXP];
    const int tid = threadIdx.x;
    const int s = blockIdx.x * 256 + tid;
    if (tid < NEXP) lcnt[tid] = 0;
    __syncthreads();
    const int e = slot_expert[s];
    const unsigned long long key = slot_key[s];
    const int lpos = atomicAdd(&lcnt[e], 1);        // LDS atomic: cheap
    __syncthreads();
    if (tid < NEXP) lbase[tid] = lcnt[tid] ? atomicAdd(&counts[tid], lcnt[tid]) : 0;
    __syncthreads();
    buckets[(size_t)e * NSLOT + lbase[e] + lpos] = key;
}

// ---------------- keep mask: one WAVE per slot, lane-parallel rank scan ----
__global__ __launch_bounds__(256) void keep_wave_kernel(
        const int* __restrict__ slot_expert,
        const unsigned long long* __restrict__ slot_key,
        const int* __restrict__ counts,
        const unsigned long long* __restrict__ buckets,
        int* __restrict__ slot_keep) {
    const int wv   = threadIdx.x >> 6;
    const int lane = threadIdx.x & 63;
    const int s    = blockIdx.x * 4 + wv;
    const int e    = slot_expert[s];
    const int c    = counts[e];
    int kp = 1;
    if (c > CAPE) {
        const unsigned long long k = slot_key[s];
        const unsigned long long* bk = buckets + (size_t)e * NSLOT;
        int rank = 0;
        for (int i = lane; i < c; i += 64) rank += (bk[i] > k) ? 1 : 0;
#pragma unroll
        for (int off = 32; off > 0; off >>= 1) rank += __shfl_down(rank, off, 64);
        kp = (__shfl(rank, 0, 64) < CAPE) ? 1 : 0;
    }
    if (lane == 0) slot_keep[s] = kp;
}

// ---- compact: elist (+slot_pos), LDS-aggregated (64 blocks x 256 thr) -----
__global__ __launch_bounds__(256) void compact_kernel(
        const int* __restrict__ slot_expert,
        const int* __restrict__ slot_keep,
        int* __restrict__ ecount,
        int* __restrict__ elist,
        int* __restrict__ slot_pos) {
    __shared__ int lcnt[NEXP];
    __shared__ int lbase[NEXP];
    const int tid = threadIdx.x;
    const int s = blockIdx.x * 256 + tid;
    if (tid < NEXP) lcnt[tid] = 0;
    __syncthreads();
    const int e  = slot_expert[s];
    const int kp = slot_keep[s];
    int lpos = 0;
    if (kp) lpos = atomicAdd(&lcnt[e], 1);
    __syncthreads();
    if (tid < NEXP) lbase[tid] = lcnt[tid] ? atomicAdd(&ecount[tid], lcnt[tid]) : 0;
    __syncthreads();
    if (kp) {
        int p = lbase[e] + lpos;
        elist[e * CAPE + p] = s;
        if (slot_pos) slot_pos[s] = e * CAPE + p;
    }
}

// ------- base (atomic-fallback path only): out[t] = (dropped g sum)*x[t] ---
__global__ void base_kernel(const float* __restrict__ x,
                            const int* __restrict__ keep,
                            const float* __restrict__ gate,
                            float* __restrict__ out) {
    int i = blockIdx.x * blockDim.x + threadIdx.x;   // float4 index
    int t = i >> 8;                                  // 256 float4 per row
    float c = 0.f;
    if (!keep[2 * t])     c += gate[2 * t];
    if (!keep[2 * t + 1]) c += gate[2 * t + 1];
    floatx4 v = ((const floatx4*)x)[i];
    ((floatx4*)out)[i] = v * c;
}

// ---------------- fp32 -> bf16 conversion (weights) ------------------------
__global__ void cvt_kernel(const float* __restrict__ src,
                           unsigned short* __restrict__ dst, int n4) {
    int i = blockIdx.x * blockDim.x + threadIdx.x;
    if (i >= n4) return;
    floatx4 v = ((const floatx4*)src)[i];
    ushort4v o;
    o[0] = f2bf(v[0]); o[1] = f2bf(v[1]); o[2] = f2bf(v[2]); o[3] = f2bf(v[3]);
    ((ushort4v*)dst)[i] = o;
}

// --------- grouped expert GEMM: 256x128 tile, BK=32, 2 blocks/CU -----------
// Round-1 post-mortem: 1 block/CU lockstep => LDS-burst and MFMA-burst
// strictly alternate (serialize). Fix: 512 blocks (grid 8x4x16) with 48 KB
// LDS and <=128 VGPR so TWO independent blocks co-reside per CU; one
// block's ds_read/stage phase overlaps the other's MFMA phase (m114 TLP).
//
// LDS rows are 64 B (BK=32). Read fragment (row=l15-group, 16B block q)
// would be an 8-way bank conflict; XOR swizzle pos = q ^ ((row>>1)&3)
// makes every quarter-wave hit 32 distinct banks (2-way wave-level = free).
// Staging keeps the LDS destination LINEAR (global_load_lds requirement)
// and inverse-swizzles the GLOBAL source k-block: j = (lane&3)^((lane>>3)&3).
//
// Schedule per K-tile t (double buffer cur=t&1), 2 barriers/tile:
//   [vmcnt(3): tile-t loads landed] bar1 ; ds_read frags ; MFMA(setprio) ;
//   bar2 (all reads of buf[cur] done) ; STAGE(t+2 -> buf[cur])
// vmcnt never drains to 0 except the last tile.
template <bool STORE_YS>
__global__ __launch_bounds__(512, 4)
void moe_gemm(const unsigned short* __restrict__ Xb,
              const unsigned short* __restrict__ Wb,
              const float* __restrict__ eb,
              const int* __restrict__ elist,
              const int* __restrict__ ecount,
              const float* __restrict__ slot_gate,
              float* __restrict__ ys,
              float* __restrict__ out) {
    __shared__ unsigned short As[2][256 * 32];   // 16 KB x2
    __shared__ unsigned short Bs[2][128 * 32];   //  8 KB x2

    const int e  = blockIdx.z;
    const int ne = ecount[e];
    const int m0 = blockIdx.y * 256;
    if (m0 >= ne) return;
    const int n0   = blockIdx.x * 128;
    const int tid  = threadIdx.x;
    const int wv   = tid >> 6;
    const int lane = tid & 63;
    const int q    = lane >> 4;
    const int l15  = lane & 15;
    const int wm   = (wv >> 1) * 64;   // wave M offset (4 M-waves)
    const int wn   = (wv & 1) * 64;    // wave N offset (2 N-waves)

    // --- staging source pointers (K-invariant) ---
    // wave wv stages rows [wv*16, wv*16+16) (+128 for A's 2nd instr); thread
    // lane L covers row srow = wv*16 + (L>>2), LDS k-pos L&3, so its global
    // k-block is j = (L&3) ^ ((row>>1)&3) = (L&3) ^ ((L>>3)&3).
    const int srow = wv * 16 + (lane >> 2);           // 0..127
    const int jsrc = (lane & 3) ^ ((lane >> 3) & 3);
    const unsigned short* gA0;
    const unsigned short* gA1;
    {
        int m = m0 + srow;
        int slot = elist[e * CAPE + (m < ne ? m : 0)];
        gA0 = Xb + (size_t)(slot >> 1) * DIM + jsrc * 8;
        m = m0 + 128 + srow;
        slot = elist[e * CAPE + (m < ne ? m : 0)];
        gA1 = Xb + (size_t)(slot >> 1) * DIM + jsrc * 8;
    }
    const unsigned short* gB0 =
        Wb + (size_t)e * DIM * DIM + (size_t)(n0 + srow) * DIM + jsrc * 8;

#define STAGE(b, k0) do { \
    GLOAD_LDS16(gA0 + (k0), &As[b][(wv * 16) * 32]); \
    GLOAD_LDS16(gA1 + (k0), &As[b][(128 + wv * 16) * 32]); \
    GLOAD_LDS16(gB0 + (k0), &Bs[b][(wv * 16) * 32]); } while (0)

    // --- prologue: tiles 0,1 in flight ---
    STAGE(0, 0);
    STAGE(1, 32);

    // read-side offsets (shorts): row*32 + pos*8, pos = q ^ ((l15>>1)&3)
    const int swz  = (q ^ ((l15 >> 1) & 3)) * 8;
    const int aoff = (wm + l15) * 32 + swz;
    const int boff = (wn + l15) * 32 + swz;

    floatx4 acc[4][4] = {};
    short8 a[4], b[4];

    for (int t = 0; t < 32; t++) {
        const int cur = t & 1;
        if (t == 31) { asm volatile("s_waitcnt vmcnt(0)" ::: "memory"); }
        else         { asm volatile("s_waitcnt vmcnt(3)" ::: "memory"); }
        __builtin_amdgcn_sched_barrier(0);
        RAW_BARRIER();                       // tile-t data visible to all

        const unsigned short* A_ = &As[cur][0];
        const unsigned short* B_ = &Bs[cur][0];
#pragma unroll
        for (int fi = 0; fi < 4; fi++) a[fi] = *(const short8*)(A_ + aoff + fi * 512);
#pragma unroll
        for (int fj = 0; fj < 4; fj++) b[fj] = *(const short8*)(B_ + boff + fj * 512);

        __builtin_amdgcn_s_setprio(1);
#pragma unroll
        for (int fi = 0; fi < 4; fi++)
#pragma unroll
            for (int fj = 0; fj < 4; fj++)
                acc[fi][fj] = __builtin_amdgcn_mfma_f32_16x16x32_bf16(
                    a[fi], b[fj], acc[fi][fj], 0, 0, 0);
        __builtin_amdgcn_s_setprio(0);
        RAW_BARRIER();                       // all reads of buf[cur] complete

        if (t + 2 < 32) STAGE(cur, (t + 2) * 32);   // overwrite buf[cur]
    }
#undef STAGE

    // --- epilogue: C/D 16x16 layout col=lane&15, row=q*4+r ---
    float ebv[4];
#pragma unroll
    for (int fj = 0; fj < 4; fj++)
        ebv[fj] = eb[e * DIM + n0 + wn + fj * 16 + l15];
#pragma unroll
    for (int fi = 0; fi < 4; fi++) {
        const int mrow = m0 + wm + fi * 16 + q * 4;
#pragma unroll
        for (int r = 0; r < 4; r++) {
            int m = mrow + r;
            if (m >= ne) continue;
            if (STORE_YS) {
                float* yrow = ys + ((size_t)e * CAPE + m) * DIM + n0 + wn;
#pragma unroll
                for (int fj = 0; fj < 4; fj++)
                    yrow[fj * 16 + l15] = acc[fi][fj][r] + ebv[fj];
            } else {
                int slot = elist[e * CAPE + m];
                int tok  = slot >> 1;
                float g  = slot_gate[slot];
                float* orow = out + (size_t)tok * DIM + n0 + wn;
#pragma unroll
                for (int fj = 0; fj < 4; fj++)
                    atomicAdd(orow + fj * 16 + l15, g * (acc[fi][fj][r] + ebv[fj]));
            }
        }
    }
}

// ---------------- combine: out = sum_k g_k * (keep ? ys[pos] : x) ----------
__global__ void combine_kernel(const float* __restrict__ x,
                               const float* __restrict__ ys,
                               const int* __restrict__ keep,
                               const int* __restrict__ pos,
                               const float* __restrict__ gate,
                               float* __restrict__ out) {
    int i = blockIdx.x * 256 + threadIdx.x;   // float4 index
    int t = i >> 8;
    int c = i & 255;
    int s0 = 2 * t, s1 = s0 + 1;
    floatx4 xv = ((const floatx4*)x)[i];
    float g0 = gate[s0], g1 = gate[s1];
    floatx4 r;
    if (keep[s0]) {
        floatx4 y0 = ((const floatx4*)ys)[((size_t)pos[s0] << 8) + c];
        r = y0 * g0;
    } else r = xv * g0;
    if (keep[s1]) {
        floatx4 y1 = ((const floatx4*)ys)[((size_t)pos[s1] << 8) + c];
        r += y1 * g1;
    } else r += xv * g1;
    ((floatx4*)out)[i] = r;
}

extern "C" void kernel_launch(void* const* d_in, const int* in_sizes, int n_in,
                              void* d_out, int out_size, void* d_ws, size_t ws_size,
                              hipStream_t stream) {
    const float* x  = (const float*)d_in[0];   // [N, D]
    const float* gw = (const float*)d_in[1];   // [D, E]
    const float* gb = (const float*)d_in[2];   // [E]
    const float* ew = (const float*)d_in[3];   // [E, D, D]
    const float* eb = (const float*)d_in[4];   // [E, D]
    float* out = (float*)d_out;                // [N, D]

    char* ws = (char*)d_ws;
    // ---- workspace layout (bytes); proven through round 4 ----
    int* counts      = (int*)(ws + 0);                   //    64 B
    int* ecount      = (int*)(ws + 64);                  //    64 B
    int* slot_expert = (int*)(ws + 256);                 //  64 KB
    int* slot_keep   = (int*)(ws + 65792);               //  64 KB
    float* slot_gate = (float*)(ws + 131328);            //  64 KB
    unsigned long long* slot_key = (unsigned long long*)(ws + 196864);  // 128 KB
    unsigned long long* buckets  = (unsigned long long*)(ws + 327936);  //   2 MB
    int* elist       = (int*)(ws + 2425088);             //  64 KB
    float* gwT       = (float*)(ws + 2490624);           //  64 KB
    unsigned short* Xb = (unsigned short*)(ws + 2556160);   // 16 MB
    unsigned short* Wb = (unsigned short*)(ws + 19333376);  // 32 MB -> end 52887808
    int* slot_pos    = (int*)(ws + 52887808);            //  64 KB (ys path only)
    int* ecount2     = (int*)(ws + 52953088);            //  unused pad
    float* ys        = (float*)(ws + 52953344);          //  64 MB (ys path only)
    const size_t WS_NEED_YS = 52953344ull + (size_t)NEXP * CAPE * DIM * 4;  // ~114.5 MB

    const bool ys_path = (ws_size >= WS_NEED_YS);
    (void)ecount2;

    hipMemsetAsync(ws, 0, 256, stream);  // zero counts + ecount

    gwt_kernel <<<64, 256, 0, stream>>>(gw, gwT);
    gate_kernel<<<N_TOK / 4, 256, 0, stream>>>(x, gwT, gb, slot_expert, slot_key,
                                               slot_gate, Xb);
    bucket_kernel<<<NSLOT / 256, 256, 0, stream>>>(slot_expert, slot_key, counts, buckets);
    keep_wave_kernel<<<NSLOT / 4, 256, 0, stream>>>(slot_expert, slot_key, counts,
                                                    buckets, slot_keep);
    compact_kernel<<<NSLOT / 256, 256, 0, stream>>>(slot_expert, slot_keep, ecount, elist,
                                                    ys_path ? slot_pos : nullptr);
    cvt_kernel<<<(NEXP * DIM * DIM / 4) / 256, 256, 0, stream>>>(ew, Wb, NEXP * DIM * DIM / 4);

    if (ys_path) {
        moe_gemm<true><<<dim3(8, 4, 16), 512, 0, stream>>>(Xb, Wb, eb, elist, ecount,
                                                           slot_gate, ys, out);
        combine_kernel<<<N_TOK, 256, 0, stream>>>(x, ys, slot_keep, slot_pos,
                                                  slot_gate, out);
    } else {
        base_kernel<<<(N_TOK * DIM / 4) / 256, 256, 0, stream>>>(x, slot_keep,
                                                                 slot_gate, out);
        moe_gemm<false><<<dim3(8, 4, 16), 512, 0, stream>>>(Xb, Wb, eb, elist, ecount,
                                                            slot_gate, nullptr, out);
    }
}